// Round 18
// baseline (29.361 us; speedup 1.0000x reference)
//
#include <hip/hip_runtime.h>

#define H 128
#define N 1024

// ---------------------------------------------------------------------------
// prep: byte-identical champion prep.
//   Lp[i][h] = w2[h]*(L[i][h]+b1[h]); Rt[h][j] = w2[h]*R[j][h];
//   c[j] = 0.5*sum_h Rt[h][j].
// ---------------------------------------------------------------------------
__global__ __launch_bounds__(512) void prep_kernel(
    const float* __restrict__ x, const float* __restrict__ W1,
    const float* __restrict__ b1, const float* __restrict__ W2,
    float* __restrict__ Lp, float* __restrict__ Rt, float* __restrict__ c)
{
    constexpr int PF = 8;
    __shared__ float e_s[4][H];
    __shared__ float cred[4][2];
    const int t = threadIdx.x;
    const int i0 = blockIdx.x * 4;

    if (t < 256) {                       // normalize: wave w owns row w
        const int row = t >> 6, lane = t & 63;
        const float2 v = *reinterpret_cast<const float2*>(&x[(i0 + row) * H + 2 * lane]);
        float s = v.x * v.x + v.y * v.y;
#pragma unroll
        for (int off = 32; off; off >>= 1) s += __shfl_xor(s, off);
        const float rn = 1.0f / fmaxf(sqrtf(s), 1e-12f);
        e_s[row][2 * lane]     = v.x * rn;
        e_s[row][2 * lane + 1] = v.y * rn;
    }
    __syncthreads();

    const int h = t & (H - 1);
    const int q = t >> 7;                // 0,1 -> L ; 2,3 -> R
    const int r0 = (q & 1) * 2;          // row pair {0,1} or {2,3}
    const float* Wb = W1 + (q >= 2 ? H * H : 0) + h;

    float acc0 = 0.f, acc1 = 0.f;
    float wbuf[PF];
#pragma unroll
    for (int p = 0; p < PF; ++p) wbuf[p] = Wb[p * H];

    for (int kb = 0; kb < H - PF; kb += PF) {
#pragma unroll
        for (int p = 0; p < PF; ++p) {
            const float w = wbuf[p];
            wbuf[p] = Wb[(kb + p + PF) * H];
            acc0 = fmaf(e_s[r0][kb + p],     w, acc0);
            acc1 = fmaf(e_s[r0 + 1][kb + p], w, acc1);
        }
    }
#pragma unroll
    for (int p = 0; p < PF; ++p) {
        const int k = H - PF + p;
        acc0 = fmaf(e_s[r0][k],     wbuf[p], acc0);
        acc1 = fmaf(e_s[r0 + 1][k], wbuf[p], acc1);
    }

    const float w2h = W2[h];
    if (q < 2) {
        const float bb = b1[h];
        Lp[(i0 + r0) * H + h]     = w2h * (acc0 + bb);
        Lp[(i0 + r0 + 1) * H + h] = w2h * (acc1 + bb);
    } else {
        const float v0 = w2h * acc0, v1 = w2h * acc1;
        Rt[h * N + (i0 + r0)]     = v0;
        Rt[h * N + (i0 + r0 + 1)] = v1;
        float s0 = v0, s1 = v1;          // c_j partial sums over h
#pragma unroll
        for (int off = 32; off; off >>= 1) {
            s0 += __shfl_xor(s0, off);
            s1 += __shfl_xor(s1, off);
        }
        const int wv = t >> 6;           // 4..7
        if ((t & 63) == 0) { cred[wv - 4][0] = s0; cred[wv - 4][1] = s1; }
    }
    __syncthreads();
    if (t < 4) {
        const int r = t;
        c[i0 + r] = 0.5f * (cred[(r >> 1) * 2][r & 1] + cred[(r >> 1) * 2 + 1][r & 1]);
    }
}

// ---------------------------------------------------------------------------
// adj: h-split-across-waves, REGISTER-PINNED A (delta vs R17).
//   R17's VGPR=92 proved the compiler rematerialized the A-loads in-loop
//   (slow R8 pattern). Fix: asm keep-alive pins a[4][32]+sg[32] in VGPRs
//   (opaque asm -> no remat). Rt prefetch deepened 2 -> 4 (256-cyc lead).
//   wave = (tau = j-half, omg = h-slice [32*omg, 32*omg+32)).
//   Main loop: 2 float4 Rt loads + 64 VALU per h; zero LDS, zero cross-lane,
//   all-static indexing. Epilogue: 64 KB partial dump, 1 barrier, 4-way
//   sum + c_j, champion block softmax.
// ---------------------------------------------------------------------------
__global__ __launch_bounds__(512, 2) void adj_kernel(
    const float* __restrict__ Lp, const float* __restrict__ Rt,
    const float* __restrict__ W2, const float* __restrict__ c,
    float* __restrict__ out)
{
    __shared__ float part[8][4][512];    // 64 KB partials
    __shared__ float red_m[4][8];
    __shared__ float red_s[4][8];

    const int t = threadIdx.x;
    const int lane = t & 63, wave = t >> 6;
    const int i0 = blockIdx.x * 4;
    const int tau = wave >> 2;           // j-team: [512*tau, 512*tau+512)
    const int omg = wave & 3;            // h-slice base
    const int hbase = 32 * omg;
    const int jb = tau * 512 + 4 * lane; // + 256*k, k=0,1

    // ---- A (4 rows x 32 h) and signs into registers, PINNED ----
    float a[4][32];
#pragma unroll
    for (int r = 0; r < 4; ++r) {
        const float4* ap = reinterpret_cast<const float4*>(&Lp[(i0 + r) * H + hbase]);
#pragma unroll
        for (int q = 0; q < 8; ++q) {
            const float4 v = ap[q];
            a[r][4 * q + 0] = v.x; a[r][4 * q + 1] = v.y;
            a[r][4 * q + 2] = v.z; a[r][4 * q + 3] = v.w;
        }
    }
    float sg[32];
    {
        const float4* wp = reinterpret_cast<const float4*>(&W2[hbase]);
#pragma unroll
        for (int q = 0; q < 8; ++q) {
            const float4 wv = wp[q];
            sg[4 * q + 0] = (wv.x >= 0.f) ? 0.5f : -0.5f;
            sg[4 * q + 1] = (wv.y >= 0.f) ? 0.5f : -0.5f;
            sg[4 * q + 2] = (wv.z >= 0.f) ? 0.5f : -0.5f;
            sg[4 * q + 3] = (wv.w >= 0.f) ? 0.5f : -0.5f;
        }
    }
    // Opaque keep-alives: compiler cannot rematerialize through these, so
    // the 160 values MUST stay VGPR-resident across the loop.
#pragma unroll
    for (int r = 0; r < 4; ++r)
#pragma unroll
        for (int hh = 0; hh < 32; ++hh)
            asm volatile("" : "+v"(a[r][hh]));
#pragma unroll
    for (int hh = 0; hh < 32; ++hh)
        asm volatile("" : "+v"(sg[hh]));

    // ---- main loop over this wave's 32 h-rows, PF=4 rotating float4x2 ----
    float4 acc[4][2];
#pragma unroll
    for (int r = 0; r < 4; ++r)
#pragma unroll
        for (int k = 0; k < 2; ++k) { acc[r][k].x = 0.f; acc[r][k].y = 0.f;
                                      acc[r][k].z = 0.f; acc[r][k].w = 0.f; }

    const float* Rp = Rt + hbase * N + jb;
    float4 rb[4][2];
#pragma unroll
    for (int p = 0; p < 4; ++p) {
        rb[p][0] = *reinterpret_cast<const float4*>(Rp + p * N);
        rb[p][1] = *reinterpret_cast<const float4*>(Rp + p * N + 256);
    }

#pragma unroll
    for (int hh = 0; hh < 32; ++hh) {
        const float4 r0 = rb[hh & 3][0];
        const float4 r1 = rb[hh & 3][1];
        if (hh + 4 < 32) {
            rb[hh & 3][0] = *reinterpret_cast<const float4*>(Rp + (hh + 4) * N);
            rb[hh & 3][1] = *reinterpret_cast<const float4*>(Rp + (hh + 4) * N + 256);
        }
        const float s = sg[hh];
#pragma unroll
        for (int r = 0; r < 4; ++r) {
            const float av = a[r][hh];
            acc[r][0].x = fmaf(s, fabsf(av + r0.x), acc[r][0].x);
            acc[r][0].y = fmaf(s, fabsf(av + r0.y), acc[r][0].y);
            acc[r][0].z = fmaf(s, fabsf(av + r0.z), acc[r][0].z);
            acc[r][0].w = fmaf(s, fabsf(av + r0.w), acc[r][0].w);
            acc[r][1].x = fmaf(s, fabsf(av + r1.x), acc[r][1].x);
            acc[r][1].y = fmaf(s, fabsf(av + r1.y), acc[r][1].y);
            acc[r][1].z = fmaf(s, fabsf(av + r1.z), acc[r][1].z);
            acc[r][1].w = fmaf(s, fabsf(av + r1.w), acc[r][1].w);
        }
    }

    // ---- dump partials to LDS ----
#pragma unroll
    for (int r = 0; r < 4; ++r) {
        *reinterpret_cast<float4*>(&part[wave][r][4 * lane])       = acc[r][0];
        *reinterpret_cast<float4*>(&part[wave][r][4 * lane + 256]) = acc[r][1];
    }
    __syncthreads();

    // ---- reduce 4 h-slice partials + c_j; thread t owns j0 = 2t, 2t+1 ----
    const int j0 = 2 * t;
    const int tj = j0 >> 9;              // team of this j
    const int jl = j0 & 511;
    const float2 cj = *reinterpret_cast<const float2*>(&c[j0]);
    float accx[4], accy[4];
#pragma unroll
    for (int r = 0; r < 4; ++r) {
        float sx = 0.f, sy = 0.f;
#pragma unroll
        for (int w = 0; w < 4; ++w) {
            const float2 p = *reinterpret_cast<const float2*>(&part[4 * tj + w][r][jl]);
            sx += p.x; sy += p.y;
        }
        accx[r] = sx + cj.x;
        accy[r] = sy + cj.y;
    }

    // ---- block softmax over j (champion verbatim) ----
#pragma unroll
    for (int ii = 0; ii < 4; ++ii) {
        float m = fmaxf(accx[ii], accy[ii]);
#pragma unroll
        for (int off = 32; off; off >>= 1) m = fmaxf(m, __shfl_xor(m, off));
        if (lane == 0) red_m[ii][wave] = m;
    }
    __syncthreads();

    float mm[4];
#pragma unroll
    for (int ii = 0; ii < 4; ++ii) {
        float m = red_m[ii][0];
#pragma unroll
        for (int w = 1; w < 8; ++w) m = fmaxf(m, red_m[ii][w]);
        mm[ii] = m;
    }

#pragma unroll
    for (int ii = 0; ii < 4; ++ii) {
        accx[ii] = expf(accx[ii] - mm[ii]);
        accy[ii] = expf(accy[ii] - mm[ii]);
        float s = accx[ii] + accy[ii];
#pragma unroll
        for (int off = 32; off; off >>= 1) s += __shfl_xor(s, off);
        if (lane == 0) red_s[ii][wave] = s;
    }
    __syncthreads();

#pragma unroll
    for (int ii = 0; ii < 4; ++ii) {
        float s = red_s[ii][0];
#pragma unroll
        for (int w = 1; w < 8; ++w) s += red_s[ii][w];
        const float r = 1.0f / s;
        float2 o;
        o.x = accx[ii] * r;
        o.y = accy[ii] * r;
        *reinterpret_cast<float2*>(&out[(i0 + ii) * N + j0]) = o;
    }
}

extern "C" void kernel_launch(void* const* d_in, const int* in_sizes, int n_in,
                              void* d_out, int out_size, void* d_ws, size_t ws_size,
                              hipStream_t stream) {
    const float* x  = (const float*)d_in[0];   // (N,H)
    const float* W1 = (const float*)d_in[1];   // (2H,H)
    const float* b1 = (const float*)d_in[2];   // (H,)
    const float* W2 = (const float*)d_in[3];   // (H,1)
    // d_in[4] = b2 — cancels under softmax, not needed.
    float* out = (float*)d_out;

    float* Lp = (float*)d_ws;        // N*H
    float* Rt = Lp + N * H;          // H*N (transposed, w2-scaled)
    float* cc = Rt + H * N;          // N

    prep_kernel<<<N / 4, 512, 0, stream>>>(x, W1, b1, W2, Lp, Rt, cc);
    adj_kernel<<<N / 4, 512, 0, stream>>>(Lp, Rt, W2, cc, out);
}

// Round 19
// 25.413 us; speedup vs baseline: 1.1553x; 1.1553x over previous
//
#include <hip/hip_runtime.h>

#define H 128
#define N 1024

// ---------------------------------------------------------------------------
// FINAL CHAMPION (reproduced 25.43 / 25.50 / 25.58 us; noise ±0.1).
//
// Math: row-softmax is invariant to row-constants, so with
//   u_h = w2[h]*(L[i][h]+b1[h]+R[j][h]) = Lp[i][h]+Rt[h][j],
//   sum_h w2*relu(.) = const_i + c_j + sum_h s_h*|u_h|, s_h = ±0.5.
// b2 and const_i cancel; c_j precomputed (pre-halved).
//
// prep: grid N/4 = 256 blocks x 512 threads (8 waves/CU).
//   waves 0-3 L2-normalize rows (shuffle reduce); quarter q = t>>7 picks
//   L/R half of W1, row pair {0,1}/{2,3}; PF=8 register-pipelined W1 loads.
//   Lp[i][h] = w2[h]*(L+b1)  (coalesced row-major stores)
//   Rt[h][j] = w2[h]*R       (transposed for adj's coalesced j-stream)
//   c[j] = 0.5*sum_h Rt[h][j] (shuffle + cred reduction)
// ---------------------------------------------------------------------------
__global__ __launch_bounds__(512) void prep_kernel(
    const float* __restrict__ x, const float* __restrict__ W1,
    const float* __restrict__ b1, const float* __restrict__ W2,
    float* __restrict__ Lp, float* __restrict__ Rt, float* __restrict__ c)
{
    constexpr int PF = 8;
    __shared__ float e_s[4][H];
    __shared__ float cred[4][2];
    const int t = threadIdx.x;
    const int i0 = blockIdx.x * 4;

    if (t < 256) {                       // normalize: wave w owns row w
        const int row = t >> 6, lane = t & 63;
        const float2 v = *reinterpret_cast<const float2*>(&x[(i0 + row) * H + 2 * lane]);
        float s = v.x * v.x + v.y * v.y;
#pragma unroll
        for (int off = 32; off; off >>= 1) s += __shfl_xor(s, off);
        const float rn = 1.0f / fmaxf(sqrtf(s), 1e-12f);
        e_s[row][2 * lane]     = v.x * rn;
        e_s[row][2 * lane + 1] = v.y * rn;
    }
    __syncthreads();

    const int h = t & (H - 1);
    const int q = t >> 7;                // 0,1 -> L ; 2,3 -> R
    const int r0 = (q & 1) * 2;          // row pair {0,1} or {2,3}
    const float* Wb = W1 + (q >= 2 ? H * H : 0) + h;

    float acc0 = 0.f, acc1 = 0.f;
    float wbuf[PF];
#pragma unroll
    for (int p = 0; p < PF; ++p) wbuf[p] = Wb[p * H];

    for (int kb = 0; kb < H - PF; kb += PF) {
#pragma unroll
        for (int p = 0; p < PF; ++p) {
            const float w = wbuf[p];
            wbuf[p] = Wb[(kb + p + PF) * H];
            acc0 = fmaf(e_s[r0][kb + p],     w, acc0);
            acc1 = fmaf(e_s[r0 + 1][kb + p], w, acc1);
        }
    }
#pragma unroll
    for (int p = 0; p < PF; ++p) {
        const int k = H - PF + p;
        acc0 = fmaf(e_s[r0][k],     wbuf[p], acc0);
        acc1 = fmaf(e_s[r0 + 1][k], wbuf[p], acc1);
    }

    const float w2h = W2[h];
    if (q < 2) {
        const float bb = b1[h];
        Lp[(i0 + r0) * H + h]     = w2h * (acc0 + bb);
        Lp[(i0 + r0 + 1) * H + h] = w2h * (acc1 + bb);
    } else {
        const float v0 = w2h * acc0, v1 = w2h * acc1;
        Rt[h * N + (i0 + r0)]     = v0;
        Rt[h * N + (i0 + r0 + 1)] = v1;
        float s0 = v0, s1 = v1;          // c_j partial sums over h
#pragma unroll
        for (int off = 32; off; off >>= 1) {
            s0 += __shfl_xor(s0, off);
            s1 += __shfl_xor(s1, off);
        }
        const int wv = t >> 6;           // 4..7
        if ((t & 63) == 0) { cred[wv - 4][0] = s0; cred[wv - 4][1] = s1; }
    }
    __syncthreads();
    if (t < 4) {                         // c[i0+r]: combine the 2 waves per row
        const int r = t;
        c[i0 + r] = 0.5f * (cred[(r >> 1) * 2][r & 1] + cred[(r >> 1) * 2 + 1][r & 1]);
    }
}

// ---------------------------------------------------------------------------
// adj: grid N/4 = 256 blocks x 512 threads (8 waves -> 2 waves/SIMD).
//   thread t: rows i0..i0+3, cols j0 = 2t, 2t+1.
//   logit'[i][j] = c[j] + sum_h s_h * |Lp[i][h] + Rt[h][j]|,  s_h = ±0.5
//   Inner loop: 2 VALU/element (v_add + v_fma with |.| input modifier),
//   PF=8 rotating float2 R-prefetch, Lp via one b128 LDS broadcast per h,
//   sgn via b32 LDS broadcast. Block-local softmax over j.
//   // Falsified single-deltas (each slower): PF=16 (+2.4us), SALU sign
//   // (+2.2), readlane A (+11), VMEM-uniform A (+4.7), JJ=4/256thr (+1.3),
//   // j-split+combine (+4.5), sign-partition (+4..8), h-split reg-A
//   // (+2.2..+3.9, compiler won't hold the array resident: VGPR 92/128).
// ---------------------------------------------------------------------------
__global__ __launch_bounds__(512) void adj_kernel(
    const float* __restrict__ Lp, const float* __restrict__ Rt,
    const float* __restrict__ W2, const float* __restrict__ c,
    float* __restrict__ out)
{
    constexpr int II = 4, PF = 8;
    __shared__ float LsT[H][4];
    __shared__ float sgn[H];
    __shared__ float red_m[II][8];
    __shared__ float red_s[II][8];

    const int t = threadIdx.x;
    const int lane = t & 63, wave = t >> 6;
    const int i0 = blockIdx.x * II;
    const int j0 = t * 2;

    if (t < H) {
        sgn[t] = (W2[t] >= 0.f) ? 0.5f : -0.5f;
        float4 lv;
        lv.x = Lp[(i0 + 0) * H + t];
        lv.y = Lp[(i0 + 1) * H + t];
        lv.z = Lp[(i0 + 2) * H + t];
        lv.w = Lp[(i0 + 3) * H + t];
        *reinterpret_cast<float4*>(&LsT[t][0]) = lv;
    }
    const float2 cj = *reinterpret_cast<const float2*>(&c[j0]);
    __syncthreads();

    float accx[II], accy[II];
#pragma unroll
    for (int ii = 0; ii < II; ++ii) { accx[ii] = cj.x; accy[ii] = cj.y; }

    float2 rbuf[PF];
#pragma unroll
    for (int p = 0; p < PF; ++p)
        rbuf[p] = *reinterpret_cast<const float2*>(&Rt[p * N + j0]);

    for (int hb = 0; hb < H - PF; hb += PF) {
#pragma unroll
        for (int p = 0; p < PF; ++p) {
            const int h = hb + p;
            const float2 r = rbuf[p];
            rbuf[p] = *reinterpret_cast<const float2*>(&Rt[(h + PF) * N + j0]);
            const float4 lv = *reinterpret_cast<const float4*>(&LsT[h][0]);
            const float s = sgn[h];
            const float* lp = &lv.x;
#pragma unroll
            for (int ii = 0; ii < II; ++ii) {
                accx[ii] = fmaf(s, fabsf(lp[ii] + r.x), accx[ii]);
                accy[ii] = fmaf(s, fabsf(lp[ii] + r.y), accy[ii]);
            }
        }
    }
#pragma unroll
    for (int p = 0; p < PF; ++p) {       // tail, no prefetch
        const int h = H - PF + p;
        const float2 r = rbuf[p];
        const float4 lv = *reinterpret_cast<const float4*>(&LsT[h][0]);
        const float s = sgn[h];
        const float* lp = &lv.x;
#pragma unroll
        for (int ii = 0; ii < II; ++ii) {
            accx[ii] = fmaf(s, fabsf(lp[ii] + r.x), accx[ii]);
            accy[ii] = fmaf(s, fabsf(lp[ii] + r.y), accy[ii]);
        }
    }

    // ---- softmax over j (block = full row) ----
#pragma unroll
    for (int ii = 0; ii < II; ++ii) {
        float m = fmaxf(accx[ii], accy[ii]);
#pragma unroll
        for (int off = 32; off; off >>= 1) m = fmaxf(m, __shfl_xor(m, off));
        if (lane == 0) red_m[ii][wave] = m;
    }
    __syncthreads();

    float mm[II];
#pragma unroll
    for (int ii = 0; ii < II; ++ii) {
        float m = red_m[ii][0];
#pragma unroll
        for (int w = 1; w < 8; ++w) m = fmaxf(m, red_m[ii][w]);
        mm[ii] = m;
    }

#pragma unroll
    for (int ii = 0; ii < II; ++ii) {
        accx[ii] = expf(accx[ii] - mm[ii]);
        accy[ii] = expf(accy[ii] - mm[ii]);
        float s = accx[ii] + accy[ii];
#pragma unroll
        for (int off = 32; off; off >>= 1) s += __shfl_xor(s, off);
        if (lane == 0) red_s[ii][wave] = s;
    }
    __syncthreads();

#pragma unroll
    for (int ii = 0; ii < II; ++ii) {
        float s = red_s[ii][0];
#pragma unroll
        for (int w = 1; w < 8; ++w) s += red_s[ii][w];
        const float r = 1.0f / s;
        float2 o;
        o.x = accx[ii] * r;
        o.y = accy[ii] * r;
        *reinterpret_cast<float2*>(&out[(i0 + ii) * N + j0]) = o;
    }
}

extern "C" void kernel_launch(void* const* d_in, const int* in_sizes, int n_in,
                              void* d_out, int out_size, void* d_ws, size_t ws_size,
                              hipStream_t stream) {
    const float* x  = (const float*)d_in[0];   // (N,H)
    const float* W1 = (const float*)d_in[1];   // (2H,H)
    const float* b1 = (const float*)d_in[2];   // (H,)
    const float* W2 = (const float*)d_in[3];   // (H,1)
    // d_in[4] = b2 — cancels under softmax, not needed.
    float* out = (float*)d_out;

    float* Lp = (float*)d_ws;        // N*H
    float* Rt = Lp + N * H;          // H*N (transposed, w2-scaled)
    float* cc = Rt + H * N;          // N

    prep_kernel<<<N / 4, 512, 0, stream>>>(x, W1, b1, W2, Lp, Rt, cc);
    adj_kernel<<<N / 4, 512, 0, stream>>>(Lp, Rt, W2, cc, out);
}

// Round 20
// 25.389 us; speedup vs baseline: 1.1564x; 1.0010x over previous
//
#include <hip/hip_runtime.h>

#define H 128
#define N 1024

// ---------------------------------------------------------------------------
// prep: byte-identical champion prep.
//   Lp[i][h] = w2[h]*(L[i][h]+b1[h]); Rt[h][j] = w2[h]*R[j][h];
//   c[j] = 0.5*sum_h Rt[h][j].
// ---------------------------------------------------------------------------
__global__ __launch_bounds__(512) void prep_kernel(
    const float* __restrict__ x, const float* __restrict__ W1,
    const float* __restrict__ b1, const float* __restrict__ W2,
    float* __restrict__ Lp, float* __restrict__ Rt, float* __restrict__ c)
{
    constexpr int PF = 8;
    __shared__ float e_s[4][H];
    __shared__ float cred[4][2];
    const int t = threadIdx.x;
    const int i0 = blockIdx.x * 4;

    if (t < 256) {                       // normalize: wave w owns row w
        const int row = t >> 6, lane = t & 63;
        const float2 v = *reinterpret_cast<const float2*>(&x[(i0 + row) * H + 2 * lane]);
        float s = v.x * v.x + v.y * v.y;
#pragma unroll
        for (int off = 32; off; off >>= 1) s += __shfl_xor(s, off);
        const float rn = 1.0f / fmaxf(sqrtf(s), 1e-12f);
        e_s[row][2 * lane]     = v.x * rn;
        e_s[row][2 * lane + 1] = v.y * rn;
    }
    __syncthreads();

    const int h = t & (H - 1);
    const int q = t >> 7;                // 0,1 -> L ; 2,3 -> R
    const int r0 = (q & 1) * 2;          // row pair {0,1} or {2,3}
    const float* Wb = W1 + (q >= 2 ? H * H : 0) + h;

    float acc0 = 0.f, acc1 = 0.f;
    float wbuf[PF];
#pragma unroll
    for (int p = 0; p < PF; ++p) wbuf[p] = Wb[p * H];

    for (int kb = 0; kb < H - PF; kb += PF) {
#pragma unroll
        for (int p = 0; p < PF; ++p) {
            const float w = wbuf[p];
            wbuf[p] = Wb[(kb + p + PF) * H];
            acc0 = fmaf(e_s[r0][kb + p],     w, acc0);
            acc1 = fmaf(e_s[r0 + 1][kb + p], w, acc1);
        }
    }
#pragma unroll
    for (int p = 0; p < PF; ++p) {
        const int k = H - PF + p;
        acc0 = fmaf(e_s[r0][k],     wbuf[p], acc0);
        acc1 = fmaf(e_s[r0 + 1][k], wbuf[p], acc1);
    }

    const float w2h = W2[h];
    if (q < 2) {
        const float bb = b1[h];
        Lp[(i0 + r0) * H + h]     = w2h * (acc0 + bb);
        Lp[(i0 + r0 + 1) * H + h] = w2h * (acc1 + bb);
    } else {
        const float v0 = w2h * acc0, v1 = w2h * acc1;
        Rt[h * N + (i0 + r0)]     = v0;
        Rt[h * N + (i0 + r0 + 1)] = v1;
        float s0 = v0, s1 = v1;          // c_j partial sums over h
#pragma unroll
        for (int off = 32; off; off >>= 1) {
            s0 += __shfl_xor(s0, off);
            s1 += __shfl_xor(s1, off);
        }
        const int wv = t >> 6;           // 4..7
        if ((t & 63) == 0) { cred[wv - 4][0] = s0; cred[wv - 4][1] = s1; }
    }
    __syncthreads();
    if (t < 4) {
        const int r = t;
        c[i0 + r] = 0.5f * (cred[(r >> 1) * 2][r & 1] + cred[(r >> 1) * 2 + 1][r & 1]);
    }
}

// ---------------------------------------------------------------------------
// adj: champion skeleton, SINGLE DELTA — per-8-group sgn preload.
//   Instead of one b32 sgn read per h-step (8 per group), read the group's
//   8 signs as TWO static-offset float4 LDS reads into registers; each
//   unrolled step consumes a compile-time-indexed register. LDS instrs/CU
//   drop 2048 -> 1280 (-37%) with NO new scalar/cross-lane dependencies
//   (unlike the falsified SALU-select/readlane variants). Everything else
//   byte-identical: 512 thr, II=4 x TJ=2, b128 LsT broadcast, PF=8
//   rotating float2 Rt prefetch, block-local softmax.
// ---------------------------------------------------------------------------
__global__ __launch_bounds__(512) void adj_kernel(
    const float* __restrict__ Lp, const float* __restrict__ Rt,
    const float* __restrict__ W2, const float* __restrict__ c,
    float* __restrict__ out)
{
    constexpr int II = 4, PF = 8;
    __shared__ float LsT[H][4];
    __shared__ __align__(16) float sgn[H];
    __shared__ float red_m[II][8];
    __shared__ float red_s[II][8];

    const int t = threadIdx.x;
    const int lane = t & 63, wave = t >> 6;
    const int i0 = blockIdx.x * II;
    const int j0 = t * 2;

    if (t < H) {
        sgn[t] = (W2[t] >= 0.f) ? 0.5f : -0.5f;
        float4 lv;
        lv.x = Lp[(i0 + 0) * H + t];
        lv.y = Lp[(i0 + 1) * H + t];
        lv.z = Lp[(i0 + 2) * H + t];
        lv.w = Lp[(i0 + 3) * H + t];
        *reinterpret_cast<float4*>(&LsT[t][0]) = lv;
    }
    const float2 cj = *reinterpret_cast<const float2*>(&c[j0]);
    __syncthreads();

    float accx[II], accy[II];
#pragma unroll
    for (int ii = 0; ii < II; ++ii) { accx[ii] = cj.x; accy[ii] = cj.y; }

    float2 rbuf[PF];
#pragma unroll
    for (int p = 0; p < PF; ++p)
        rbuf[p] = *reinterpret_cast<const float2*>(&Rt[p * N + j0]);

    for (int hb = 0; hb < H - PF; hb += PF) {
        // group sgn preload: 2 LDS float4 reads replace 8 b32 reads
        const float4 sga = *reinterpret_cast<const float4*>(&sgn[hb]);
        const float4 sgb = *reinterpret_cast<const float4*>(&sgn[hb + 4]);
        const float sgv[8] = {sga.x, sga.y, sga.z, sga.w,
                              sgb.x, sgb.y, sgb.z, sgb.w};
#pragma unroll
        for (int p = 0; p < PF; ++p) {
            const int h = hb + p;
            const float2 r = rbuf[p];
            rbuf[p] = *reinterpret_cast<const float2*>(&Rt[(h + PF) * N + j0]);
            const float4 lv = *reinterpret_cast<const float4*>(&LsT[h][0]);
            const float s = sgv[p];          // compile-time index
            const float* lp = &lv.x;
#pragma unroll
            for (int ii = 0; ii < II; ++ii) {
                accx[ii] = fmaf(s, fabsf(lp[ii] + r.x), accx[ii]);
                accy[ii] = fmaf(s, fabsf(lp[ii] + r.y), accy[ii]);
            }
        }
    }
    {   // tail: h = 120..127, no prefetch
        const float4 sga = *reinterpret_cast<const float4*>(&sgn[H - PF]);
        const float4 sgb = *reinterpret_cast<const float4*>(&sgn[H - PF + 4]);
        const float sgv[8] = {sga.x, sga.y, sga.z, sga.w,
                              sgb.x, sgb.y, sgb.z, sgb.w};
#pragma unroll
        for (int p = 0; p < PF; ++p) {
            const int h = H - PF + p;
            const float2 r = rbuf[p];
            const float4 lv = *reinterpret_cast<const float4*>(&LsT[h][0]);
            const float s = sgv[p];
            const float* lp = &lv.x;
#pragma unroll
            for (int ii = 0; ii < II; ++ii) {
                accx[ii] = fmaf(s, fabsf(lp[ii] + r.x), accx[ii]);
                accy[ii] = fmaf(s, fabsf(lp[ii] + r.y), accy[ii]);
            }
        }
    }

    // ---- softmax over j (block = full row) ----
#pragma unroll
    for (int ii = 0; ii < II; ++ii) {
        float m = fmaxf(accx[ii], accy[ii]);
#pragma unroll
        for (int off = 32; off; off >>= 1) m = fmaxf(m, __shfl_xor(m, off));
        if (lane == 0) red_m[ii][wave] = m;
    }
    __syncthreads();

    float mm[II];
#pragma unroll
    for (int ii = 0; ii < II; ++ii) {
        float m = red_m[ii][0];
#pragma unroll
        for (int w = 1; w < 8; ++w) m = fmaxf(m, red_m[ii][w]);
        mm[ii] = m;
    }

#pragma unroll
    for (int ii = 0; ii < II; ++ii) {
        accx[ii] = expf(accx[ii] - mm[ii]);
        accy[ii] = expf(accy[ii] - mm[ii]);
        float s = accx[ii] + accy[ii];
#pragma unroll
        for (int off = 32; off; off >>= 1) s += __shfl_xor(s, off);
        if (lane == 0) red_s[ii][wave] = s;
    }
    __syncthreads();

#pragma unroll
    for (int ii = 0; ii < II; ++ii) {
        float s = red_s[ii][0];
#pragma unroll
        for (int w = 1; w < 8; ++w) s += red_s[ii][w];
        const float r = 1.0f / s;
        float2 o;
        o.x = accx[ii] * r;
        o.y = accy[ii] * r;
        *reinterpret_cast<float2*>(&out[(i0 + ii) * N + j0]) = o;
    }
}

extern "C" void kernel_launch(void* const* d_in, const int* in_sizes, int n_in,
                              void* d_out, int out_size, void* d_ws, size_t ws_size,
                              hipStream_t stream) {
    const float* x  = (const float*)d_in[0];   // (N,H)
    const float* W1 = (const float*)d_in[1];   // (2H,H)
    const float* b1 = (const float*)d_in[2];   // (H,)
    const float* W2 = (const float*)d_in[3];   // (H,1)
    // d_in[4] = b2 — cancels under softmax, not needed.
    float* out = (float*)d_out;

    float* Lp = (float*)d_ws;        // N*H
    float* Rt = Lp + N * H;          // H*N (transposed, w2-scaled)
    float* cc = Rt + H * N;          // N

    prep_kernel<<<N / 4, 512, 0, stream>>>(x, W1, b1, W2, Lp, Rt, cc);
    adj_kernel<<<N / 4, 512, 0, stream>>>(Lp, Rt, W2, cc, out);
}